// Round 21
// baseline (39014.407 us; speedup 1.0000x reference)
//
#include <hip/hip_runtime.h>
#include <stdint.h>
#include <math.h>

typedef unsigned int u32;

constexpr int kB = 512, kS = 128, kH = 512, kE = 256, kT = 100;
constexpr int kNG = 4 * kH; // 2048

// ---- ws layout (f32 elements) ----
constexpr size_t SZ_E = (size_t)kS * kB * kH; // 33,554,432
constexpr size_t OFF_EG  = 0;                              // EG [s][b][h]
constexpr size_t OFF_EP  = OFF_EG + SZ_E;                  // EP [s][b][h]
constexpr size_t OFF_U   = OFF_EP + SZ_E;
constexpr size_t OFF_P   = OFF_U + (size_t)kB * kS;
constexpr size_t OFF_QP  = OFF_P + (size_t)kB * kS;        // kB*kH
constexpr size_t OFF_GL  = OFF_QP + (size_t)kB * kH;       // kB*kH
constexpr size_t OFF_G   = OFF_GL + (size_t)kB * kH;       // kB*kNG (unused)
constexpr size_t OFF_HX  = OFF_G + (size_t)kB * kNG;       // kB*kH
constexpr size_t OFF_CX  = OFF_HX + (size_t)kB * kH;       // kB*kH
constexpr size_t OFF_DC  = OFF_CX + (size_t)kB * kH;       // kB*kE
constexpr size_t OFF_FM  = OFF_DC + (size_t)kB * kE;       // kB ints
constexpr size_t OFF_FMM = OFF_FM + kB;
constexpr size_t WS_FLOATS = OFF_FMM + kB;                 // ≈265 MiB (PROVEN available)

// ---------------- sentinel (bail only) ----------------
__global__ __launch_bounds__(256) void sentinel_k(float* __restrict__ outSel, float val) {
  int i = blockIdx.x * blockDim.x + threadIdx.x;
  if (i < kT * kB) outSel[i] = val;
}

// ---------------- threefry2x32 (exact JAX) ----------------
__device__ __forceinline__ u32 rotl32(u32 v, int d) { return (v << d) | (v >> (32 - d)); }

__device__ __forceinline__ void tf2x32(u32 k0, u32 k1, u32 x0, u32 x1, u32& o0, u32& o1) {
  u32 ks2 = k0 ^ k1 ^ 0x1BD11BDAu;
  x0 += k0; x1 += k1;
#define RND_(r) { x0 += x1; x1 = rotl32(x1, r); x1 ^= x0; }
  RND_(13) RND_(15) RND_(26) RND_(6)   x0 += k1;  x1 += ks2 + 1u;
  RND_(17) RND_(29) RND_(16) RND_(24)  x0 += ks2; x1 += k0 + 2u;
  RND_(13) RND_(15) RND_(26) RND_(6)   x0 += k0;  x1 += k1 + 3u;
  RND_(17) RND_(29) RND_(16) RND_(24)  x0 += k1;  x1 += ks2 + 4u;
  RND_(13) RND_(15) RND_(26) RND_(6)   x0 += ks2; x1 += k0 + 5u;
#undef RND_
  o0 = x0; o1 = x1;
}

__device__ __forceinline__ float sigf(float x) { return 1.0f / (1.0f + expf(-x)); }

// ------- E precompute (R15 original: [s][b][h] writes) -------
__global__ __launch_bounds__(512) void precompute_e(const float* __restrict__ ctx,
                                                    const float* __restrict__ Wg,
                                                    const float* __restrict__ bg,
                                                    const float* __restrict__ Wp,
                                                    const float* __restrict__ bp,
                                                    float* __restrict__ EG,
                                                    float* __restrict__ EP) {
  __shared__ float ctxs[8][512];
  __shared__ float Wgs[512][33];
  __shared__ float Wps[512][33];
  const int tid = threadIdx.x;
  const size_t m0 = (size_t)blockIdx.x * 8;
  for (int idx = tid; idx < 8 * 512; idx += 512) {
    ctxs[idx >> 9][idx & 511] = ctx[(m0 + (idx >> 9)) * 512 + (idx & 511)];
  }
  float accg[8] = {}, accp[8] = {};
  for (int k0 = 0; k0 < 512; k0 += 32) {
    __syncthreads();
    for (int idx = tid; idx < 512 * 32; idx += 512) {
      int row = idx >> 5, kk = idx & 31;
      Wgs[row][kk] = Wg[(size_t)row * 512 + k0 + kk];
      Wps[row][kk] = Wp[(size_t)row * 512 + k0 + kk];
    }
    __syncthreads();
#pragma unroll 4
    for (int kk = 0; kk < 32; ++kk) {
      float wg = Wgs[tid][kk], wp = Wps[tid][kk];
#pragma unroll
      for (int mi = 0; mi < 8; ++mi) {
        float a = ctxs[mi][k0 + kk];
        accg[mi] = fmaf(a, wg, accg[mi]);
        accp[mi] = fmaf(a, wp, accp[mi]);
      }
    }
  }
  float bgv = bg[tid], bpv = bp[tid];
#pragma unroll
  for (int mi = 0; mi < 8; ++mi) {
    size_t m = m0 + mi;
    EG[m * 512 + tid] = accg[mi] + bgv;
    EP[m * 512 + tid] = accp[mi] + bpv;
  }
}

// ---------------- init state ----------------
__global__ __launch_bounds__(256) void init_k(const float* __restrict__ dec_in,
                                              const float* __restrict__ hx0,
                                              const float* __restrict__ cx0,
                                              float* __restrict__ dec, float* __restrict__ hx,
                                              float* __restrict__ cx, int* __restrict__ fm,
                                              int* __restrict__ fmm) {
  int i = blockIdx.x * blockDim.x + threadIdx.x;
  if (i < kB * kH) { hx[i] = hx0[i]; cx[i] = cx0[i]; }
  if (i < kB * kE) dec[i] = dec_in[i];
  if (i < kB) { fm[i] = 1; fmm[i] = 1; }
}

// ======= lstm_fused v2 (proven in R19/R20): grid 512; 4 gate-outputs/thread =======
__global__ __launch_bounds__(512) void lstm_fused(
    const float* __restrict__ DC, const float* __restrict__ Wi, const float* __restrict__ bi,
    const float* __restrict__ Wh, const float* __restrict__ bh, float* __restrict__ HX,
    float* __restrict__ CX) {
  __shared__ float Ws[128][33];
  __shared__ float As[16][32];
  const int bid = blockIdx.x;
  const int tid = threadIdx.x;
  const int h0 = (bid & 15) * 32;
  const int b0 = (bid >> 4) * 16;
  const int hl = tid & 31;
  const int bs = tid >> 5; // 0..15
  float accI[4] = {}, accH[4] = {};
  for (int k0 = 0; k0 < 768; k0 += 32) {
    const bool isI = (k0 < 256);
    __syncthreads();
    {
      int bb = tid >> 5, kk = tid & 31;
      int k = k0 + kk;
      As[bb][kk] = isI ? DC[(size_t)(b0 + bb) * kE + k] : HX[(size_t)(b0 + bb) * kH + (k - 256)];
    }
    for (int idx = tid; idx < 128 * 32; idx += 512) {
      int r = idx >> 5, kk = idx & 31;
      int grow = ((r >> 5) << 9) + h0 + (r & 31);
      int k = k0 + kk;
      Ws[r][kk] = isI ? Wi[(size_t)grow * kE + k] : Wh[(size_t)grow * kH + (k - 256)];
    }
    __syncthreads();
    if (isI) {
#pragma unroll 8
      for (int kk = 0; kk < 32; ++kk) {
        float a = As[bs][kk];
#pragma unroll
        for (int g = 0; g < 4; ++g) accI[g] = fmaf(a, Ws[g * 32 + hl][kk], accI[g]);
      }
    } else {
#pragma unroll 8
      for (int kk = 0; kk < 32; ++kk) {
        float a = As[bs][kk];
#pragma unroll
        for (int g = 0; g < 4; ++g) accH[g] = fmaf(a, Ws[g * 32 + hl][kk], accH[g]);
      }
    }
  }
  const int h = h0 + hl;
  const int b = b0 + bs;
  float ig = ((accI[0] + bi[h]) + accH[0]) + bh[h];
  float fg = ((accI[1] + bi[512 + h]) + accH[1]) + bh[512 + h];
  float cgv = ((accI[2] + bi[1024 + h]) + accH[2]) + bh[1024 + h];
  float og = ((accI[3] + bi[1536 + h]) + accH[3]) + bh[1536 + h];
  size_t off = (size_t)b * kH + h;
  float cyv = sigf(fg) * CX[off] + sigf(ig) * tanhf(cgv);
  float hyv = sigf(og) * tanhf(cyv);
  CX[off] = cyv;
  HX[off] = hyv;
}

// ======= fused_step: R15 VERBATIM ([s][b][h] E) + unroll hints on att loops =======
__global__ __launch_bounds__(512) void fused_step(
    const float* __restrict__ EG, const float* __restrict__ EP, const float* __restrict__ gWq,
    const float* __restrict__ gbq, const float* __restrict__ gv, const float* __restrict__ pWq,
    const float* __restrict__ pbq, const float* __restrict__ pv, const float* __restrict__ emb,
    const int* __restrict__ counts, float* __restrict__ HX, float* __restrict__ DC,
    int* __restrict__ fmask, int* __restrict__ fmmask, float* __restrict__ outP,
    float* __restrict__ outSel, int t) {
  __shared__ float Ws[512][33];
  __shared__ float hs[512];
  __shared__ float qs[512];
  __shared__ float gvs[512];
  __shared__ float gls[512];
  __shared__ float u[128], sL[128], ex[128], kv[128];
  __shared__ float mred, sred, sMult;
  __shared__ int sIdx;

  const int b = blockIdx.x;
  const int tid = threadIdx.x;
  const int wave = tid >> 6, lane = tid & 63;

  hs[tid] = HX[(size_t)b * kH + tid];
  gvs[tid] = gv[tid];
  __syncthreads();

  // ---- qp1 = hs @ gWq^T + gbq ----
  {
    float acc = 0.f;
    for (int k0 = 0; k0 < 512; k0 += 32) {
      __syncthreads();
      for (int idx = tid; idx < 512 * 32; idx += 512) {
        int row = idx >> 5, kk = idx & 31;
        Ws[row][kk] = gWq[(size_t)row * 512 + k0 + kk];
      }
      __syncthreads();
#pragma unroll 8
      for (int kk = 0; kk < 32; ++kk) acc = fmaf(hs[k0 + kk], Ws[tid][kk], acc);
    }
    qs[tid] = acc + gbq[tid];
  }
  __syncthreads();

  // ---- att1 u[s]: wave-per-s, lanes split h, shuffle reduce ----
#pragma unroll 2
  for (int r = 0; r < 16; ++r) {
    int s = wave + 8 * r;
    const float* row = EG + ((size_t)s * kB + b) * kH;
    float a = 0.f;
#pragma unroll
    for (int i = 0; i < 8; ++i) {
      int h = lane + 64 * i;
      a = fmaf(gvs[h], tanhf(qs[h] + row[h]), a);
    }
#pragma unroll
    for (int off = 32; off > 0; off >>= 1) a += __shfl_xor(a, off);
    if (lane == 0) u[s] = a;
  }
  __syncthreads();

  if (tid == 0) { float m = u[0]; for (int i = 1; i < 128; ++i) m = fmaxf(m, u[i]); mred = m; }
  __syncthreads();
  if (tid < 128) ex[tid] = expf(u[tid] - mred);
  __syncthreads();
  if (tid == 0) { float s = 0.f; for (int i = 0; i < 128; ++i) s += ex[i]; sred = s; }
  __syncthreads();
  if (tid < 128) ex[tid] = ex[tid] / sred;
  __syncthreads();

  // ---- gl[h] = serial_s fmaf(EG[s][b][h], P[s]) ----
  {
    float acc = 0.f;
#pragma unroll 4
    for (int s = 0; s < 128; ++s) acc = fmaf(EG[((size_t)s * kB + b) * kH + tid], ex[s], acc);
    gls[tid] = acc;
  }
  __syncthreads();

  // ---- qp2 = gls @ pWq^T + pbq ----
  {
    float acc = 0.f;
    for (int k0 = 0; k0 < 512; k0 += 32) {
      __syncthreads();
      for (int idx = tid; idx < 512 * 32; idx += 512) {
        int row = idx >> 5, kk = idx & 31;
        Ws[row][kk] = pWq[(size_t)row * 512 + k0 + kk];
      }
      __syncthreads();
#pragma unroll 8
      for (int kk = 0; kk < 32; ++kk) acc = fmaf(gls[k0 + kk], Ws[tid][kk], acc);
    }
    qs[tid] = acc + pbq[tid];
    gvs[tid] = pv[tid];
  }
  __syncthreads();

  // ---- att2 u[s] on EP ----
#pragma unroll 2
  for (int r = 0; r < 16; ++r) {
    int s = wave + 8 * r;
    const float* row = EP + ((size_t)s * kB + b) * kH;
    float a = 0.f;
#pragma unroll
    for (int i = 0; i < 8; ++i) {
      int h = lane + 64 * i;
      a = fmaf(gvs[h], tanhf(qs[h] + row[h]), a);
    }
#pragma unroll
    for (int off = 32; off > 0; off >>= 1) a += __shfl_xor(a, off);
    if (lane == 0) u[s] = a;
  }
  __syncthreads();

  // ---- logits, softmax, gumbel, argmax, masks, gather ----
  if (tid < 128) sL[tid] = 10.0f * tanhf(u[tid]);
  __syncthreads();
  if (tid == 0) { float m = sL[0]; for (int i = 1; i < 128; ++i) m = fmaxf(m, sL[i]); mred = m; }
  __syncthreads();
  if (tid < 128) ex[tid] = expf(sL[tid] - mred);
  __syncthreads();
  if (tid == 0) { float s = 0.f; for (int i = 0; i < 128; ++i) s += ex[i]; sred = s; }
  __syncthreads();
  if (tid < 128) {
    u32 fk0, fk1;
    tf2x32(0u, 42u, 0u, (u32)t, fk0, fk1);
    u32 j = (u32)(b * kS + tid);
    u32 y0, y1;
    tf2x32(fk0, fk1, 0u, j, y0, y1);
    u32 bits = y0 ^ y1; // partitionable 32-bit path
    float f = __uint_as_float(0x3f800000u | (bits >> 9)) - 1.0f;
    float uu = (f > 0.0f) ? f : 1.17549435082228751e-38f;
    float z = -logf(-logf(uu));
    kv[tid] = sL[tid] + z;
  }
  __syncthreads();
  if (tid == 0) {
    float best = kv[0];
    int ia = 0;
    for (int i = 1; i < 128; ++i)
      if (kv[i] > best) { best = kv[i]; ia = i; } // first-index tie-break
    int fm = fmask[b], fmm = fmmask[b];
    int idx = ia * fm;
    outSel[(size_t)t * kB + b] = (float)idx;
    fmask[b] = (idx != 0) ? fm : 0;
    fmmask[b] = (t == counts[b]) ? 0 : fmm;
    sIdx = idx;
    sMult = (float)(fm * fmm);
  }
  __syncthreads();
  if (tid < 128) outP[((size_t)b * kT + t) * kS + tid] = (ex[tid] / sred) * sMult;
  if (tid < 256) DC[(size_t)b * kE + tid] = emb[((size_t)sIdx * kB + b) * kE + tid];
}

// ---------------- final hx/cx copy ----------------
__global__ __launch_bounds__(256) void final_copy(const float* __restrict__ hx,
                                                  const float* __restrict__ cx,
                                                  float* __restrict__ o2, float* __restrict__ o3) {
  int i = blockIdx.x * blockDim.x + threadIdx.x;
  if (i < kB * kH) { o2[i] = hx[i]; o3[i] = cx[i]; }
}

extern "C" void kernel_launch(void* const* d_in, const int* in_sizes, int n_in, void* d_out,
                              int out_size, void* d_ws, size_t ws_size, hipStream_t stream) {
  const float* dec_in = (const float*)d_in[0];
  const float* emb = (const float*)d_in[1];
  const float* hx0 = (const float*)d_in[2];
  const float* cx0 = (const float*)d_in[3];
  const float* ctx = (const float*)d_in[4];
  const int* counts = (const int*)d_in[5];
  const float* Wi = (const float*)d_in[7];
  const float* bi = (const float*)d_in[8];
  const float* Wh = (const float*)d_in[9];
  const float* bh = (const float*)d_in[10];
  const float* gWq = (const float*)d_in[11];
  const float* gbq = (const float*)d_in[12];
  const float* gWr = (const float*)d_in[13];
  const float* gbr = (const float*)d_in[14];
  const float* gv = (const float*)d_in[15];
  const float* pWq = (const float*)d_in[16];
  const float* pbq = (const float*)d_in[17];
  const float* pWr = (const float*)d_in[18];
  const float* pbr = (const float*)d_in[19];
  const float* pv = (const float*)d_in[20];

  float* out = (float*)d_out;
  float* outP = out;                          // (B*T, S)
  float* outSel = out + (size_t)kB * kT * kS; // (T, B)
  float* outHx = outSel + (size_t)kT * kB;    // (B, H)
  float* outCx = outHx + (size_t)kB * kH;     // (B, H)

  if (ws_size < WS_FLOATS * sizeof(float)) {
    double wsMB = (double)ws_size / (1024.0 * 1024.0);
    if (wsMB > 80000.0) wsMB = 80000.0;
    hipLaunchKernelGGL(sentinel_k, dim3((kT * kB + 255) / 256), dim3(256), 0, stream, outSel,
                       (float)(1000.0 + wsMB));
    return;
  }

  float* base = (float*)d_ws;
  float* EG = base + OFF_EG;
  float* EP = base + OFF_EP;
  float* HX = base + OFF_HX;
  float* CX = base + OFF_CX;
  float* DC = base + OFF_DC;
  int* FM  = (int*)(base + OFF_FM);
  int* FMM = (int*)(base + OFF_FMM);

  hipLaunchKernelGGL(precompute_e, dim3(kS * kB / 8), dim3(512), 0, stream, ctx, gWr, gbr, pWr,
                     pbr, EG, EP);
  hipLaunchKernelGGL(init_k, dim3(kB * kH / 256), dim3(256), 0, stream, dec_in, hx0, cx0, DC, HX,
                     CX, FM, FMM);

  for (int t = 0; t < kT; ++t) {
    hipLaunchKernelGGL(lstm_fused, dim3(512), dim3(512), 0, stream, DC, Wi, bi, Wh, bh, HX, CX);
    hipLaunchKernelGGL(fused_step, dim3(kB), dim3(512), 0, stream, EG, EP, gWq, gbq, gv, pWq, pbq,
                       pv, emb, counts, HX, DC, FM, FMM, outP, outSel, t);
  }
  hipLaunchKernelGGL(final_copy, dim3(kB * kH / 256), dim3(256), 0, stream, HX, CX, outHx, outCx);
}

// Round 22
// 31090.921 us; speedup vs baseline: 1.2548x; 1.2548x over previous
//
#include <hip/hip_runtime.h>
#include <stdint.h>
#include <math.h>

typedef unsigned int u32;

constexpr int kB = 512, kS = 128, kH = 512, kE = 256, kT = 100;

// ---- ws layout (f32 elements); total 69,206,016 floats = 276.8 MB < proven 277.9 MB ----
constexpr size_t SZ_E = (size_t)kS * kB * kH; // 33,554,432
constexpr size_t OFF_EG  = 0;                       // EG [s][b][h]
constexpr size_t OFF_EP  = OFF_EG + SZ_E;           // EP [s][b][h]
constexpr size_t OFF_WIT = OFF_EP + SZ_E;           // WiT [256][2048]
constexpr size_t OFF_WHT = OFF_WIT + (size_t)kE * 2048;   // WhT [512][2048]
constexpr size_t OFF_GQT = OFF_WHT + (size_t)kH * 2048;   // gWqT [512][512]
constexpr size_t OFF_PQT = OFF_GQT + (size_t)kH * kH;     // pWqT [512][512]
constexpr size_t WS_FLOATS = OFF_PQT + (size_t)kH * kH;

// ---------------- sentinel (bail only) ----------------
__global__ __launch_bounds__(256) void sentinel_k(float* __restrict__ outSel, float val) {
  int i = blockIdx.x * blockDim.x + threadIdx.x;
  if (i < kT * kB) outSel[i] = val;
}

// ---------------- threefry2x32 (exact JAX) ----------------
__device__ __forceinline__ u32 rotl32(u32 v, int d) { return (v << d) | (v >> (32 - d)); }

__device__ __forceinline__ void tf2x32(u32 k0, u32 k1, u32 x0, u32 x1, u32& o0, u32& o1) {
  u32 ks2 = k0 ^ k1 ^ 0x1BD11BDAu;
  x0 += k0; x1 += k1;
#define RND_(r) { x0 += x1; x1 = rotl32(x1, r); x1 ^= x0; }
  RND_(13) RND_(15) RND_(26) RND_(6)   x0 += k1;  x1 += ks2 + 1u;
  RND_(17) RND_(29) RND_(16) RND_(24)  x0 += ks2; x1 += k0 + 2u;
  RND_(13) RND_(15) RND_(26) RND_(6)   x0 += k0;  x1 += k1 + 3u;
  RND_(17) RND_(29) RND_(16) RND_(24)  x0 += k1;  x1 += ks2 + 4u;
  RND_(13) RND_(15) RND_(26) RND_(6)   x0 += ks2; x1 += k0 + 5u;
#undef RND_
  o0 = x0; o1 = x1;
}

__device__ __forceinline__ float sigf(float x) { return 1.0f / (1.0f + expf(-x)); }

// ------- E precompute (R15 original, proven) -------
__global__ __launch_bounds__(512) void precompute_e(const float* __restrict__ ctx,
                                                    const float* __restrict__ Wg,
                                                    const float* __restrict__ bg,
                                                    const float* __restrict__ Wp,
                                                    const float* __restrict__ bp,
                                                    float* __restrict__ EG,
                                                    float* __restrict__ EP) {
  __shared__ float ctxs[8][512];
  __shared__ float Wgs[512][33];
  __shared__ float Wps[512][33];
  const int tid = threadIdx.x;
  const size_t m0 = (size_t)blockIdx.x * 8;
  for (int idx = tid; idx < 8 * 512; idx += 512) {
    ctxs[idx >> 9][idx & 511] = ctx[(m0 + (idx >> 9)) * 512 + (idx & 511)];
  }
  float accg[8] = {}, accp[8] = {};
  for (int k0 = 0; k0 < 512; k0 += 32) {
    __syncthreads();
    for (int idx = tid; idx < 512 * 32; idx += 512) {
      int row = idx >> 5, kk = idx & 31;
      Wgs[row][kk] = Wg[(size_t)row * 512 + k0 + kk];
      Wps[row][kk] = Wp[(size_t)row * 512 + k0 + kk];
    }
    __syncthreads();
#pragma unroll 4
    for (int kk = 0; kk < 32; ++kk) {
      float wg = Wgs[tid][kk], wp = Wps[tid][kk];
#pragma unroll
      for (int mi = 0; mi < 8; ++mi) {
        float a = ctxs[mi][k0 + kk];
        accg[mi] = fmaf(a, wg, accg[mi]);
        accp[mi] = fmaf(a, wp, accp[mi]);
      }
    }
  }
  float bgv = bg[tid], bpv = bp[tid];
#pragma unroll
  for (int mi = 0; mi < 8; ++mi) {
    size_t m = m0 + mi;
    EG[m * 512 + tid] = accg[mi] + bgv;
    EP[m * 512 + tid] = accp[mi] + bpv;
  }
}

// ------- one-time W transpose: out[k*O + o] = in[o*K + k] (coalesced writes) -------
__global__ __launch_bounds__(256) void transpose_k(const float* __restrict__ in,
                                                   float* __restrict__ out, int O, int K) {
  int flat = blockIdx.x * 256 + threadIdx.x;
  if (flat < O * K) {
    int o = flat % O, k = flat / O;
    out[flat] = in[(size_t)o * K + k];
  }
}

// =================== persistent per-b kernel: whole T loop, no sync ===================
__global__ __launch_bounds__(512) void persist_k(
    const float* __restrict__ EG, const float* __restrict__ EP, const float* __restrict__ WiT,
    const float* __restrict__ WhT, const float* __restrict__ bi, const float* __restrict__ bh,
    const float* __restrict__ gQT, const float* __restrict__ gbq, const float* __restrict__ gv,
    const float* __restrict__ pQT, const float* __restrict__ pbq, const float* __restrict__ pv,
    const float* __restrict__ emb, const int* __restrict__ counts,
    const float* __restrict__ dec_in, const float* __restrict__ hx0,
    const float* __restrict__ cx0, float* __restrict__ outP, float* __restrict__ outSel,
    float* __restrict__ outHx, float* __restrict__ outCx) {
  __shared__ float hs[512], cs[512], dec[256], qs[512], gls[512];
  __shared__ float gvs[512], pvs[512];
  __shared__ float u[128], sL[128], ex[128], kv[128];
  __shared__ float mred, sred, sMult;
  __shared__ int sIdx, sFM, sFMM;

  const int b = blockIdx.x;
  const int tid = threadIdx.x;
  const int wave = tid >> 6, lane = tid & 63;

  hs[tid] = hx0[(size_t)b * kH + tid];
  cs[tid] = cx0[(size_t)b * kH + tid];
  if (tid < kE) dec[tid] = dec_in[(size_t)b * kE + tid];
  gvs[tid] = gv[tid];
  pvs[tid] = pv[tid];
  if (tid == 0) { sFM = 1; sFMM = 1; }
  const int cnt = counts[b];
  // per-thread constants
  const float biR0 = bi[tid], biR1 = bi[512 + tid], biR2 = bi[1024 + tid], biR3 = bi[1536 + tid];
  const float bhR0 = bh[tid], bhR1 = bh[512 + tid], bhR2 = bh[1024 + tid], bhR3 = bh[1536 + tid];
  const float gbqR = gbq[tid], pbqR = pbq[tid];
  __syncthreads();

  for (int t = 0; t < kT; ++t) {
    // ======== LSTM: thread h=tid computes its 4 gate dots (same chains as lstm_fused) ======
    float aI0 = 0.f, aI1 = 0.f, aI2 = 0.f, aI3 = 0.f;
#pragma unroll 4
    for (int k = 0; k < kE; ++k) {
      float a = dec[k];
      const float* wr = WiT + (size_t)k * 2048 + tid;
      aI0 = fmaf(a, wr[0], aI0);
      aI1 = fmaf(a, wr[512], aI1);
      aI2 = fmaf(a, wr[1024], aI2);
      aI3 = fmaf(a, wr[1536], aI3);
    }
    float aH0 = 0.f, aH1 = 0.f, aH2 = 0.f, aH3 = 0.f;
#pragma unroll 4
    for (int k = 0; k < kH; ++k) {
      float a = hs[k];
      const float* wr = WhT + (size_t)k * 2048 + tid;
      aH0 = fmaf(a, wr[0], aH0);
      aH1 = fmaf(a, wr[512], aH1);
      aH2 = fmaf(a, wr[1024], aH2);
      aH3 = fmaf(a, wr[1536], aH3);
    }
    float ig = ((aI0 + biR0) + aH0) + bhR0;
    float fg = ((aI1 + biR1) + aH1) + bhR1;
    float cgv = ((aI2 + biR2) + aH2) + bhR2;
    float og = ((aI3 + biR3) + aH3) + bhR3;
    float cyv = sigf(fg) * cs[tid] + sigf(ig) * tanhf(cgv);
    float hyv = sigf(og) * tanhf(cyv);
    __syncthreads(); // all reads of hs done before overwrite
    cs[tid] = cyv;
    hs[tid] = hyv;
    __syncthreads();

    // ======== qp1 = hs @ gWq^T + gbq (ascending-k fmaf; coalesced gQT) ========
    {
      float acc = 0.f;
#pragma unroll 8
      for (int k = 0; k < kH; ++k) acc = fmaf(hs[k], gQT[(size_t)k * kH + tid], acc);
      qs[tid] = acc + gbqR;
    }
    __syncthreads();

    // ======== att1 u[s]: wave-per-s, lanes split h, shuffle reduce (R15 math) ========
#pragma unroll 2
    for (int r = 0; r < 16; ++r) {
      int s = wave + 8 * r;
      const float* row = EG + ((size_t)s * kB + b) * kH;
      float a = 0.f;
#pragma unroll
      for (int i = 0; i < 8; ++i) {
        int h = lane + 64 * i;
        a = fmaf(gvs[h], tanhf(qs[h] + row[h]), a);
      }
#pragma unroll
      for (int off = 32; off > 0; off >>= 1) a += __shfl_xor(a, off);
      if (lane == 0) u[s] = a;
    }
    __syncthreads();

    if (tid == 0) { float m = u[0]; for (int i = 1; i < 128; ++i) m = fmaxf(m, u[i]); mred = m; }
    __syncthreads();
    if (tid < 128) ex[tid] = expf(u[tid] - mred);
    __syncthreads();
    if (tid == 0) { float s = 0.f; for (int i = 0; i < 128; ++i) s += ex[i]; sred = s; }
    __syncthreads();
    if (tid < 128) ex[tid] = ex[tid] / sred;
    __syncthreads();

    // ======== gl[h] = serial_s fmaf(EG[s][b][h], P[s]) (R15 order) ========
    {
      float acc = 0.f;
#pragma unroll 4
      for (int s = 0; s < 128; ++s) acc = fmaf(EG[((size_t)s * kB + b) * kH + tid], ex[s], acc);
      gls[tid] = acc;
    }
    __syncthreads();

    // ======== qp2 = gls @ pWq^T + pbq ========
    {
      float acc = 0.f;
#pragma unroll 8
      for (int k = 0; k < kH; ++k) acc = fmaf(gls[k], pQT[(size_t)k * kH + tid], acc);
      qs[tid] = acc + pbqR;
    }
    __syncthreads();

    // ======== att2 u[s] on EP ========
#pragma unroll 2
    for (int r = 0; r < 16; ++r) {
      int s = wave + 8 * r;
      const float* row = EP + ((size_t)s * kB + b) * kH;
      float a = 0.f;
#pragma unroll
      for (int i = 0; i < 8; ++i) {
        int h = lane + 64 * i;
        a = fmaf(pvs[h], tanhf(qs[h] + row[h]), a);
      }
#pragma unroll
      for (int off = 32; off > 0; off >>= 1) a += __shfl_xor(a, off);
      if (lane == 0) u[s] = a;
    }
    __syncthreads();

    // ======== logits, softmax, gumbel, argmax, masks, gather (R13/R15 semantics) ========
    if (tid < 128) sL[tid] = 10.0f * tanhf(u[tid]);
    __syncthreads();
    if (tid == 0) { float m = sL[0]; for (int i = 1; i < 128; ++i) m = fmaxf(m, sL[i]); mred = m; }
    __syncthreads();
    if (tid < 128) ex[tid] = expf(sL[tid] - mred);
    __syncthreads();
    if (tid == 0) { float s = 0.f; for (int i = 0; i < 128; ++i) s += ex[i]; sred = s; }
    __syncthreads();
    if (tid < 128) {
      u32 fk0, fk1;
      tf2x32(0u, 42u, 0u, (u32)t, fk0, fk1);
      u32 j = (u32)(b * kS + tid);
      u32 y0, y1;
      tf2x32(fk0, fk1, 0u, j, y0, y1);
      u32 bits = y0 ^ y1; // partitionable 32-bit path
      float f = __uint_as_float(0x3f800000u | (bits >> 9)) - 1.0f;
      float uu = (f > 0.0f) ? f : 1.17549435082228751e-38f;
      float z = -logf(-logf(uu));
      kv[tid] = sL[tid] + z;
    }
    __syncthreads();
    if (tid == 0) {
      float best = kv[0];
      int ia = 0;
      for (int i = 1; i < 128; ++i)
        if (kv[i] > best) { best = kv[i]; ia = i; } // first-index tie-break
      int fm = sFM, fmm = sFMM;
      int idx = ia * fm;
      outSel[(size_t)t * kB + b] = (float)idx;
      sFM = (idx != 0) ? fm : 0;
      sFMM = (t == cnt) ? 0 : fmm;
      sIdx = idx;
      sMult = (float)(fm * fmm);
    }
    __syncthreads();
    if (tid < 128) outP[((size_t)b * kT + t) * kS + tid] = (ex[tid] / sred) * sMult;
    if (tid < kE) dec[tid] = emb[((size_t)sIdx * kB + b) * kE + tid];
    __syncthreads(); // dec ready for next step's LSTM
  }

  outHx[(size_t)b * kH + tid] = hs[tid];
  outCx[(size_t)b * kH + tid] = cs[tid];
}

extern "C" void kernel_launch(void* const* d_in, const int* in_sizes, int n_in, void* d_out,
                              int out_size, void* d_ws, size_t ws_size, hipStream_t stream) {
  const float* dec_in = (const float*)d_in[0];
  const float* emb = (const float*)d_in[1];
  const float* hx0 = (const float*)d_in[2];
  const float* cx0 = (const float*)d_in[3];
  const float* ctx = (const float*)d_in[4];
  const int* counts = (const int*)d_in[5];
  const float* Wi = (const float*)d_in[7];
  const float* bi = (const float*)d_in[8];
  const float* Wh = (const float*)d_in[9];
  const float* bh = (const float*)d_in[10];
  const float* gWq = (const float*)d_in[11];
  const float* gbq = (const float*)d_in[12];
  const float* gWr = (const float*)d_in[13];
  const float* gbr = (const float*)d_in[14];
  const float* gv = (const float*)d_in[15];
  const float* pWq = (const float*)d_in[16];
  const float* pbq = (const float*)d_in[17];
  const float* pWr = (const float*)d_in[18];
  const float* pbr = (const float*)d_in[19];
  const float* pv = (const float*)d_in[20];

  float* out = (float*)d_out;
  float* outP = out;                          // (B*T, S)
  float* outSel = out + (size_t)kB * kT * kS; // (T, B)
  float* outHx = outSel + (size_t)kT * kB;    // (B, H)
  float* outCx = outHx + (size_t)kB * kH;     // (B, H)

  if (ws_size < WS_FLOATS * sizeof(float)) {
    double wsMB = (double)ws_size / (1024.0 * 1024.0);
    if (wsMB > 80000.0) wsMB = 80000.0;
    hipLaunchKernelGGL(sentinel_k, dim3((kT * kB + 255) / 256), dim3(256), 0, stream, outSel,
                       (float)(1000.0 + wsMB));
    return;
  }

  float* base = (float*)d_ws;
  float* EG  = base + OFF_EG;
  float* EP  = base + OFF_EP;
  float* WiT = base + OFF_WIT;
  float* WhT = base + OFF_WHT;
  float* GQT = base + OFF_GQT;
  float* PQT = base + OFF_PQT;

  hipLaunchKernelGGL(precompute_e, dim3(kS * kB / 8), dim3(512), 0, stream, ctx, gWr, gbr, pWr,
                     pbr, EG, EP);
  hipLaunchKernelGGL(transpose_k, dim3((2048 * kE + 255) / 256), dim3(256), 0, stream, Wi, WiT,
                     2048, kE);
  hipLaunchKernelGGL(transpose_k, dim3((2048 * kH + 255) / 256), dim3(256), 0, stream, Wh, WhT,
                     2048, kH);
  hipLaunchKernelGGL(transpose_k, dim3((kH * kH + 255) / 256), dim3(256), 0, stream, gWq, GQT, kH,
                     kH);
  hipLaunchKernelGGL(transpose_k, dim3((kH * kH + 255) / 256), dim3(256), 0, stream, pWq, PQT, kH,
                     kH);

  hipLaunchKernelGGL(persist_k, dim3(kB), dim3(512), 0, stream, EG, EP, WiT, WhT, bi, bh, GQT,
                     gbq, gv, PQT, pbq, pv, emb, counts, dec_in, hx0, cx0, outP, outSel, outHx,
                     outCx);
}